// Round 1
// baseline (1648.238 us; speedup 1.0000x reference)
//
#include <hip/hip_runtime.h>
#include <stdint.h>

#define NNODES 50000
#define NEDGES 400000
#define MPAD   50048   // 391 * 128
#define MTILES 391
#define ZRF    0.8f
#define GNEPS  1e-5f

typedef unsigned short u16;
typedef __bf16 bf16x8 __attribute__((ext_vector_type(8)));
typedef float  f32x4  __attribute__((ext_vector_type(4)));

// bf16 weight arena offsets (elements)
#define OFF_NODEW 0
#define OFF_NQM   32768
#define OFF_TCAT  163840
#define OFF_GAT   425984
#define OFF_CCAT  557056
#define W_TOTAL   1081344

__device__ __forceinline__ float b2f(u16 u){ union{uint32_t i; float f;} x; x.i=((uint32_t)u)<<16; return x.f; }
__device__ __forceinline__ u16 f2b(float f){ union{float f; uint32_t i;} x; x.f=f; uint32_t r=x.i+0x7FFFu+((x.i>>16)&1u); return (u16)(r>>16); }
__device__ __forceinline__ float lrelu(float x){ return x>0.f? x : 0.2f*x; }
__device__ __forceinline__ void atomicMaxF(float* a, float v){
  if (v>=0.f) atomicMax((int*)a, __float_as_int(v));
  else atomicMin((unsigned int*)a, (unsigned int)__float_as_int(v));
}

// ---------------- bf16 MFMA GEMM: out[M,N] = op(A[M,K] @ B[N,K]^T + bias) ----------------
// A row-major (lda=K, or 256/256 split across A0/A1 when SPLIT), B row-major N x K (weights).
// 128x128 tile, BK=64, 4 waves (2x2), 16x16x32 bf16 MFMA, XOR-swizzled LDS (T2-lite).
template<int RELU, int SPLIT>
__global__ __launch_bounds__(256)
void gemm_bf16(const u16* __restrict__ A0, const u16* __restrict__ A1,
               const u16* __restrict__ B, const float* __restrict__ bias,
               u16* __restrict__ out, int N, int K)
{
  __shared__ alignas(16) u16 Al[128*64];
  __shared__ alignas(16) u16 Bl[128*64];
  const int tid  = threadIdx.x;
  const int bm0  = (blockIdx.x % MTILES) * 128;
  const int bn0  = (blockIdx.x / MTILES) * 128;
  const int KT   = K >> 6;
  const int lane = tid & 63;
  const int wv   = tid >> 6;
  const int wm   = (wv >> 1) * 64;
  const int wn   = (wv & 1) * 64;
  const int lrow = lane & 15;
  const int kgrp = (lane >> 4) * 16;   // byte offset of this lane's 8-elem k-group
  const int srow = tid >> 3;           // staging row 0..31 (+32/pass)
  const int sc   = (tid & 7) * 16;     // staging byte col

  f32x4 acc[4][4] = {};
  uint4 ar[4], br[4];

#define LOADT(ktv) do { \
    int ks = (ktv) * 64; \
    const u16* Ap; int kloc, lda; \
    if (SPLIT) { lda = 256; if (ks < 256) { Ap = A0; kloc = ks; } else { Ap = A1; kloc = ks - 256; } } \
    else { Ap = A0; kloc = ks; lda = K; } \
    _Pragma("unroll") \
    for (int p = 0; p < 4; ++p) { \
      int r = srow + p * 32; \
      ar[p] = *(const uint4*)(Ap + (size_t)(bm0 + r) * lda + kloc + (sc >> 1)); \
      br[p] = *(const uint4*)(B  + (size_t)(bn0 + r) * K   + ks   + (sc >> 1)); \
    } } while (0)

  LOADT(0);
  for (int kt = 0; kt < KT; ++kt) {
    __syncthreads();
#pragma unroll
    for (int p = 0; p < 4; ++p) {
      int r = srow + p * 32;
      int off = r * 128 + (sc ^ ((r & 7) << 4));
      *(uint4*)((char*)Al + off) = ar[p];
      *(uint4*)((char*)Bl + off) = br[p];
    }
    __syncthreads();
    if (kt + 1 < KT) LOADT(kt + 1);
#pragma unroll
    for (int kk = 0; kk < 2; ++kk) {
      bf16x8 af[4], bfv[4];
      int kb = kk * 64 + kgrp;
#pragma unroll
      for (int mi = 0; mi < 4; ++mi) {
        int r = wm + mi * 16 + lrow;
        af[mi] = *(const bf16x8*)((const char*)Al + r * 128 + (kb ^ ((r & 7) << 4)));
      }
#pragma unroll
      for (int ni = 0; ni < 4; ++ni) {
        int r = wn + ni * 16 + lrow;
        bfv[ni] = *(const bf16x8*)((const char*)Bl + r * 128 + (kb ^ ((r & 7) << 4)));
      }
#pragma unroll
      for (int mi = 0; mi < 4; ++mi)
#pragma unroll
        for (int ni = 0; ni < 4; ++ni)
          acc[mi][ni] = __builtin_amdgcn_mfma_f32_16x16x32_bf16(af[mi], bfv[ni], acc[mi][ni], 0, 0, 0);
    }
  }
#undef LOADT
  const int rb = (lane >> 4) * 4;   // D: col = lane&15, row = (lane>>4)*4 + reg  [m89/m91]
#pragma unroll
  for (int ni = 0; ni < 4; ++ni) {
    int col = bn0 + wn + ni * 16 + lrow;
    float bv = bias ? bias[col] : 0.f;
#pragma unroll
    for (int mi = 0; mi < 4; ++mi) {
      int row = bm0 + wm + mi * 16 + rb;
#pragma unroll
      for (int r = 0; r < 4; ++r) {
        float v = acc[mi][ni][r] + bv;
        if (RELU) v = fmaxf(v, 0.f);
        out[(size_t)(row + r) * N + col] = f2b(v);
      }
    }
  }
}

// ---------------- setup / conversion kernels ----------------
__global__ void convw(const float* __restrict__ nodeW, const float* __restrict__ nqmW,
                      const float* __restrict__ t0W, const float* __restrict__ t1W,
                      const float* __restrict__ gatW, const float* __restrict__ c0W,
                      const float* __restrict__ c1W, u16* __restrict__ arena){
  int idx = blockIdx.x*256 + threadIdx.x;
  if (idx >= W_TOTAL) return;
  float v;
  if (idx < OFF_NQM) { v = nodeW[idx]; }
  else if (idx < OFF_TCAT){ int i = idx - OFF_NQM;  int l=i>>16; int r=(i>>8)&255; int k=i&255; v = nqmW[l*131072 + r*512 + k]; }
  else if (idx < OFF_GAT) { int i = idx - OFF_TCAT; int l=i>>17; int n=(i>>8)&511; int k=i&255;
                            const float* s = (n<256)? t1W : t0W; v = s[l*65536 + (n&255)*256 + k]; }
  else if (idx < OFF_CCAT){ int i = idx - OFF_GAT;  v = gatW[i]; }
  else                    { int i = idx - OFF_CCAT; int l=i>>18; int n=(i>>9)&511; int k=i&511;
                            const float* s = (n<256)? c1W : c0W; v = s[l*131072 + (n&255)*512 + k]; }
  arena[idx] = f2b(v);
}

__global__ void convxin(const float* __restrict__ x, u16* __restrict__ o){
  int idx = blockIdx.x*256 + threadIdx.x;
  if (idx >= MPAD*32) return;
  int n = idx >> 5; int c = (idx & 31)*4;
  float4 v = make_float4(0.f,0.f,0.f,0.f);
  if (n < NNODES) v = *(const float4*)&x[(size_t)n*128 + c];
  ushort4 r; r.x=f2b(v.x); r.y=f2b(v.y); r.z=f2b(v.z); r.w=f2b(v.w);
  *(ushort4*)&o[(size_t)n*128 + c] = r;
}

__global__ void biascat(const float* __restrict__ t1b, const float* __restrict__ t0b,
                        const float* __restrict__ c1b, const float* __restrict__ c0b,
                        float* __restrict__ tb, float* __restrict__ cb){
  int i = blockIdx.x*256 + threadIdx.x;
  if (i >= 2048) return;
  int which = i >> 10; int j = i & 1023; int l = j >> 9; int n = j & 511;
  const float* b1 = which ? c1b : t1b;
  const float* b0 = which ? c0b : t0b;
  float v = (n < 256) ? b1[l*256 + n] : b0[l*256 + n - 256];
  (which ? cb : tb)[l*512 + n] = v;
}

__global__ void qvk(const float* __restrict__ qemb, const float* __restrict__ W,
                    const float* __restrict__ b, float* __restrict__ qv){
  int h = threadIdx.x;
  float acc = b[h];
  for (int d = 0; d < 128; ++d) acc += qemb[d] * W[h*128 + d];
  qv[h] = fmaxf(acc, 0.f);
}

__global__ void qbk(const float* __restrict__ nqmW, const float* __restrict__ nqmB,
                    const float* __restrict__ qv, float* __restrict__ qb){
  int l = blockIdx.x, h = threadIdx.x;
  const float* wr = nqmW + l*131072 + h*512 + 256;
  float acc = nqmB[l*256 + h];
  for (int j = 0; j < 256; ++j) acc += wr[j] * qv[j];
  qb[l*256 + h] = acc;
}

// subgraph_mask marshalling detection: count nonzero bytes in first NNODES bytes.
__global__ void detmask(const unsigned char* __restrict__ mb, int* __restrict__ flag){
  __shared__ int cnt_s;
  if (threadIdx.x == 0) cnt_s = 0;
  __syncthreads();
  int c = 0;
  for (int i = threadIdx.x; i < NNODES; i += 1024) c += (mb[i] != 0);
  atomicAdd(&cnt_s, c);
  __syncthreads();
  if (threadIdx.x == 0) *flag = (cnt_s * 8 > NNODES * 3) ? 1 : 0;  // 1 => 1-byte bools
}

__global__ void maskmat(const void* __restrict__ m, const int* __restrict__ flag,
                        uint32_t* __restrict__ mask){
  int i = blockIdx.x*256 + threadIdx.x;
  if (i >= NNODES) return;
  int f = *flag;
  mask[i] = f ? (((const unsigned char*)m)[i] != 0) : (((const int*)m)[i] != 0);
}

// ---------------- edge sort (dst-sorted src list), done per launch ----------------
__global__ void hist(const int* __restrict__ dst, int* __restrict__ count){
  int i = blockIdx.x*256 + threadIdx.x;
  if (i < NEDGES) atomicAdd(&count[dst[i]], 1);
}

__global__ void scan50k(const int* __restrict__ count, int* __restrict__ offs, int* __restrict__ cursor){
  __shared__ int tmp[1024];
  __shared__ int carry_s;
  int t = threadIdx.x;
  if (t == 0) carry_s = 0;
  __syncthreads();
  for (int base = 0; base < NNODES; base += 1024) {
    int v = (base + t < NNODES) ? count[base + t] : 0;
    tmp[t] = v;
    __syncthreads();
    for (int d = 1; d < 1024; d <<= 1) {
      int add = (t >= d) ? tmp[t - d] : 0;
      __syncthreads();
      tmp[t] += add;
      __syncthreads();
    }
    int carry = carry_s;
    if (base + t < NNODES) {
      int excl = carry + tmp[t] - v;
      offs[base + t] = excl;
      cursor[base + t] = excl;
    }
    __syncthreads();
    if (t == 1023) carry_s = carry + tmp[1023];
    __syncthreads();
  }
  if (t == 0) offs[NNODES] = carry_s;
}

__global__ void scatter(const int* __restrict__ src, const int* __restrict__ dst,
                        int* __restrict__ cursor, int* __restrict__ ssrc){
  int i = blockIdx.x*256 + threadIdx.x;
  if (i >= NEDGES) return;
  int p = atomicAdd(&cursor[dst[i]], 1);
  ssrc[p] = src[i];
}

// ---------------- elementwise / graph kernels ----------------
__global__ void mixt(const u16* __restrict__ x01, const uint32_t* __restrict__ mask, u16* __restrict__ h){
  int idx = blockIdx.x*256 + threadIdx.x;
  if (idx >= MPAD*64) return;
  int n = idx >> 6; int c = (idx & 63)*4;
  float wa = 1.0f - ZRF;
  if (n < NNODES && mask[n]) wa = ZRF;
  float wb = 1.0f - wa;
  ushort4 a = *(const ushort4*)&x01[(size_t)n*512 + c];        // x1 (t1)
  ushort4 b = *(const ushort4*)&x01[(size_t)n*512 + 256 + c];  // x0 (t0)
  ushort4 r;
  r.x = f2b(wa*b2f(a.x) + wb*b2f(b.x));
  r.y = f2b(wa*b2f(a.y) + wb*b2f(b.y));
  r.z = f2b(wa*b2f(a.z) + wb*b2f(b.z));
  r.w = f2b(wa*b2f(a.w) + wb*b2f(b.w));
  *(ushort4*)&h[(size_t)n*256 + c] = r;
}

__global__ void dotav(const u16* __restrict__ xw, const float* __restrict__ asrc,
                      const float* __restrict__ adst, float* __restrict__ avs, float* __restrict__ avd){
  int wid = (blockIdx.x*256 + threadIdx.x) >> 6;
  int lane = threadIdx.x & 63;
  if (wid >= NNODES) return;
  ushort4 v = *(const ushort4*)&xw[(size_t)wid*256 + lane*4];
  float4 s4 = *(const float4*)&asrc[lane*4];
  float4 d4 = *(const float4*)&adst[lane*4];
  float x0=b2f(v.x), x1=b2f(v.y), x2=b2f(v.z), x3=b2f(v.w);
  float ps = x0*s4.x + x1*s4.y + x2*s4.z + x3*s4.w;
  float pd = x0*d4.x + x1*d4.y + x2*d4.z + x3*d4.w;
  for (int d = 32; d; d >>= 1){ ps += __shfl_xor(ps, d); pd += __shfl_xor(pd, d); }
  if (lane == 0){ avs[wid] = ps; avd[wid] = pd; }
}

// one wave per node: online softmax over incoming edges (+self loop), gather-accumulate xw rows
__global__ void agg(const int* __restrict__ offs, const int* __restrict__ ssrc,
                    const float* __restrict__ avs, const float* __restrict__ avd,
                    const u16* __restrict__ xw, const float* __restrict__ gbias,
                    float* __restrict__ out){
  int v = (blockIdx.x*256 + threadIdx.x) >> 6;
  int lane = threadIdx.x & 63;
  if (v >= NNODES) return;
  int o0 = offs[v], o1 = offs[v+1];
  float ad = avd[v];
  float slog = lrelu(avs[v] + ad);
  float m = slog;
  for (int i = o0 + lane; i < o1; i += 64) m = fmaxf(m, lrelu(avs[ssrc[i]] + ad));
  for (int d = 32; d; d >>= 1) m = fmaxf(m, __shfl_xor(m, d));
  float den = (lane == 0) ? __expf(slog - m) : 0.f;
  for (int i = o0 + lane; i < o1; i += 64) den += __expf(lrelu(avs[ssrc[i]] + ad) - m);
  for (int d = 32; d; d >>= 1) den += __shfl_xor(den, d);
  float rden = 1.0f / (den + 1e-16f);
  int c = lane*4;
  ushort4 xv = *(const ushort4*)&xw[(size_t)v*256 + c];
  float wgt = __expf(slog - m) * rden;
  float a0 = wgt*b2f(xv.x), a1 = wgt*b2f(xv.y), a2 = wgt*b2f(xv.z), a3 = wgt*b2f(xv.w);
  for (int i = o0; i < o1; ++i){
    int s = ssrc[i];
    float w = __expf(lrelu(avs[s] + ad) - m) * rden;
    ushort4 q = *(const ushort4*)&xw[(size_t)s*256 + c];
    a0 += w*b2f(q.x); a1 += w*b2f(q.y); a2 += w*b2f(q.z); a3 += w*b2f(q.w);
  }
  float4 bb = *(const float4*)&gbias[c];
  float4 r; r.x = a0 + bb.x; r.y = a1 + bb.y; r.z = a2 + bb.z; r.w = a3 + bb.w;
  *(float4*)&out[(size_t)v*256 + c] = r;
}

__global__ void colstats(const float* __restrict__ x, float* __restrict__ sums){
  int c = threadIdx.x;
  float s = 0.f, q = 0.f;
  for (int n = blockIdx.x; n < NNODES; n += gridDim.x){
    float v = x[(size_t)n*256 + c]; s += v; q += v*v;
  }
  atomicAdd(&sums[c], s); atomicAdd(&sums[256 + c], q);
}

__global__ void scaleshift(const float* __restrict__ sums, const float* __restrict__ w,
                           const float* __restrict__ b, const float* __restrict__ a,
                           float* __restrict__ scale, float* __restrict__ shift){
  int c = threadIdx.x;
  const float invn = 1.0f / (float)NNODES;
  float mu  = sums[c] * invn;
  float ex2 = sums[256 + c] * invn;
  float av  = a[c];
  float var = ex2 - (2.0f*av - av*av)*mu*mu;
  float sc  = w[c] / sqrtf(var + GNEPS);
  scale[c] = sc;
  shift[c] = b[c] - sc*av*mu;
}

__global__ void normf(const float* __restrict__ x, const float* __restrict__ scale,
                      const float* __restrict__ shift, u16* __restrict__ o){
  int idx = blockIdx.x*256 + threadIdx.x;
  if (idx >= MPAD*64) return;
  int n = idx >> 6; int c = (idx & 63)*4;
  float4 v  = *(const float4*)&x[(size_t)n*256 + c];
  float4 sc = *(const float4*)&scale[c];
  float4 sh = *(const float4*)&shift[c];
  ushort4 r;
  r.x = f2b(v.x*sc.x + sh.x); r.y = f2b(v.y*sc.y + sh.y);
  r.z = f2b(v.z*sc.z + sh.z); r.w = f2b(v.w*sc.w + sh.w);
  *(ushort4*)&o[(size_t)n*256 + c] = r;
}

__global__ void normb(const u16* __restrict__ x, const float* __restrict__ scale,
                      const float* __restrict__ shift, u16* __restrict__ o){
  int idx = blockIdx.x*256 + threadIdx.x;
  if (idx >= MPAD*64) return;
  int n = idx >> 6; int c = (idx & 63)*4;
  ushort4 v = *(const ushort4*)&x[(size_t)n*256 + c];
  float4 sc = *(const float4*)&scale[c];
  float4 sh = *(const float4*)&shift[c];
  ushort4 r;
  r.x = f2b(b2f(v.x)*sc.x + sh.x); r.y = f2b(b2f(v.y)*sc.y + sh.y);
  r.z = f2b(b2f(v.z)*sc.z + sh.z); r.w = f2b(b2f(v.w)*sc.w + sh.w);
  *(ushort4*)&o[(size_t)n*256 + c] = r;
}

__global__ void mixstats(const u16* __restrict__ y01, const uint32_t* __restrict__ mask,
                         u16* __restrict__ xm, float* __restrict__ sums){
  int c = threadIdx.x;
  float s = 0.f, q = 0.f;
  for (int n = blockIdx.x; n < MPAD; n += gridDim.x){
    float y1 = b2f(y01[(size_t)n*512 + c]);
    float y0 = b2f(y01[(size_t)n*512 + 256 + c]);
    float wa = 1.0f - ZRF;
    if (n < NNODES && mask[n]) wa = ZRF;
    float v = wa*y1 + (1.0f - wa)*y0;
    xm[(size_t)n*256 + c] = f2b(v);
    if (n < NNODES){ s += v; q += v*v; }
  }
  atomicAdd(&sums[c], s); atomicAdd(&sums[256 + c], q);
}

__global__ void initneg(float* __restrict__ pmax){ pmax[threadIdx.x] = -__builtin_inff(); }

__global__ void pool(const u16* __restrict__ x, const uint32_t* __restrict__ mask,
                     float* __restrict__ psum, float* __restrict__ pmax, int* __restrict__ pcnt){
  int c = threadIdx.x;
  float s = 0.f, mx = -__builtin_inff(); int cnt = 0;
  for (int n = blockIdx.x; n < NNODES; n += gridDim.x){
    if (mask[n]){
      float v = b2f(x[(size_t)n*256 + c]);
      s += v; mx = fmaxf(mx, v); cnt++;
    }
  }
  atomicAdd(&psum[c], s);
  atomicMaxF(&pmax[c], mx);
  if (c == 0) atomicAdd(pcnt, cnt);
}

__global__ void finalk(const float* __restrict__ psum, const float* __restrict__ pmax,
                       const int* __restrict__ pcnt, const float* __restrict__ W,
                       const float* __restrict__ b, float* __restrict__ out){
  int o = threadIdx.x;
  float cnt = fmaxf((float)(*pcnt), 1.0f);
  float inv = 1.0f / cnt;
  const float* wr = W + o*768;
  float acc = b[o];
  for (int j = 0; j < 256; ++j) acc += (psum[j]*inv) * wr[j];
  for (int j = 0; j < 256; ++j) acc += pmax[j] * wr[256 + j];
  for (int j = 0; j < 256; ++j) acc += psum[j] * wr[512 + j];
  out[o] = acc;
}

// ---------------- host orchestration ----------------
extern "C" void kernel_launch(void* const* d_in, const int* in_sizes, int n_in,
                              void* d_out, int out_size, void* d_ws, size_t ws_size,
                              hipStream_t stream)
{
  (void)in_sizes; (void)n_in; (void)out_size; (void)ws_size;
  const float* x_    = (const float*)d_in[0];
  const int*   eidx  = (const int*)  d_in[1];
  const float* qemb  = (const float*)d_in[3];
  const void*  mraw  =               d_in[4];
  const float* nodeW = (const float*)d_in[5];
  const float* nodeB = (const float*)d_in[6];
  const float* qinW  = (const float*)d_in[9];
  const float* qinB  = (const float*)d_in[10];
  const float* nqmW  = (const float*)d_in[11];
  const float* nqmB  = (const float*)d_in[12];
  const float* t0W   = (const float*)d_in[15];
  const float* t0B   = (const float*)d_in[16];
  const float* t1W   = (const float*)d_in[17];
  const float* t1B   = (const float*)d_in[18];
  const float* gatW  = (const float*)d_in[19];
  const float* gatAs = (const float*)d_in[20];
  const float* gatAd = (const float*)d_in[21];
  const float* gatB  = (const float*)d_in[22];
  const float* cgnW  = (const float*)d_in[23];
  const float* cgnB  = (const float*)d_in[24];
  const float* cgnA  = (const float*)d_in[25];
  const float* c0W   = (const float*)d_in[26];
  const float* c0B   = (const float*)d_in[27];
  const float* c1W   = (const float*)d_in[28];
  const float* c1B   = (const float*)d_in[29];
  const float* gnW   = (const float*)d_in[30];
  const float* gnB   = (const float*)d_in[31];
  const float* gnA   = (const float*)d_in[32];
  const float* finW  = (const float*)d_in[33];
  const float* finB  = (const float*)d_in[34];
  float* outp = (float*)d_out;

  char* p = (char*)d_ws;
  auto alloc = [&](size_t b)->char*{ char* r = p; p += (b + 511) & ~(size_t)511; return r; };
  u16*      arena = (u16*)     alloc((size_t)W_TOTAL*2);
  float*    tb    = (float*)   alloc(1024*4);
  float*    cb    = (float*)   alloc(1024*4);
  float*    qv    = (float*)   alloc(256*4);
  float*    qb    = (float*)   alloc(512*4);
  float*    scale = (float*)   alloc(256*4);
  float*    shift = (float*)   alloc(256*4);
  float*    sums  = (float*)   alloc(512*4);
  float*    psum  = (float*)   alloc(256*4);
  float*    pmax  = (float*)   alloc(256*4);
  int*      pcnt  = (int*)     alloc(256);
  int*      flag  = (int*)     alloc(256);
  uint32_t* mask  = (uint32_t*)alloc((size_t)NNODES*4);
  int*      count = (int*)     alloc((size_t)NNODES*4);
  int*      offs  = (int*)     alloc((size_t)(NNODES+1)*4);
  int*      cursor= (int*)     alloc((size_t)NNODES*4);
  int*      ssrc  = (int*)     alloc((size_t)NEDGES*4);
  float*    avs   = (float*)   alloc((size_t)NNODES*4);
  float*    avd   = (float*)   alloc((size_t)NNODES*4);
  u16*      xin   = (u16*)     alloc((size_t)MPAD*128*2);
  u16*      xb    = (u16*)     alloc((size_t)MPAD*256*2);
  u16*      xc    = (u16*)     alloc((size_t)MPAD*256*2);
  u16*      hb    = (u16*)     alloc((size_t)MPAD*256*2);
  u16*      xw    = (u16*)     alloc((size_t)MPAD*256*2);
  u16*      hn    = (u16*)     alloc((size_t)MPAD*256*2);
  u16*      xm    = (u16*)     alloc((size_t)MPAD*256*2);
  u16*      b512  = (u16*)     alloc((size_t)MPAD*512*2);
  float*    hgat  = (float*)   alloc((size_t)MPAD*256*4);

  const int* esrc = eidx;
  const int* edst = eidx + NEDGES;

  // setup: weight conversion, q-branch, mask decode, dst-sorted edge list
  convw  <<<dim3((W_TOTAL+255)/256), dim3(256), 0, stream>>>(nodeW, nqmW, t0W, t1W, gatW, c0W, c1W, arena);
  convxin<<<dim3(MPAD*32/256), dim3(256), 0, stream>>>(x_, xin);
  biascat<<<dim3(8), dim3(256), 0, stream>>>(t1B, t0B, c1B, c0B, tb, cb);
  qvk    <<<dim3(1), dim3(256), 0, stream>>>(qemb, qinW, qinB, qv);
  qbk    <<<dim3(2), dim3(256), 0, stream>>>(nqmW, nqmB, qv, qb);
  detmask<<<dim3(1), dim3(1024), 0, stream>>>((const unsigned char*)mraw, flag);
  maskmat<<<dim3((NNODES+255)/256), dim3(256), 0, stream>>>(mraw, flag, mask);
  hipMemsetAsync(count, 0, (size_t)NNODES*4, stream);
  hist   <<<dim3((NEDGES+255)/256), dim3(256), 0, stream>>>(edst, count);
  scan50k<<<dim3(1), dim3(1024), 0, stream>>>(count, offs, cursor);
  scatter<<<dim3((NEDGES+255)/256), dim3(256), 0, stream>>>(esrc, edst, cursor, ssrc);

  // x = relu(x_ @ node_in_W^T + b)
  gemm_bf16<1,0><<<dim3(MTILES*2), dim3(256), 0, stream>>>(xin, nullptr, arena+OFF_NODEW, nodeB, xb, 256, 128);

  for (int l = 0; l < 2; ++l) {
    // xc = relu(x @ nqm_W[:, :H]^T + (qb: q-part + bias))
    gemm_bf16<1,0><<<dim3(MTILES*2), dim3(256), 0, stream>>>(xb, nullptr, arena+OFF_NQM + l*65536, qb + l*256, xc, 256, 256);
    // [x1 | x0] = relu(xc @ [t1;t0]^T + b)
    gemm_bf16<1,0><<<dim3(MTILES*4), dim3(256), 0, stream>>>(xc, nullptr, arena+OFF_TCAT + l*131072, tb + l*512, b512, 512, 256);
    mixt<<<dim3(MPAD*64/256), dim3(256), 0, stream>>>(b512, mask, hb);
    // xw = h @ gat_W^T
    gemm_bf16<0,0><<<dim3(MTILES*2), dim3(256), 0, stream>>>(hb, nullptr, arena+OFF_GAT + l*65536, nullptr, xw, 256, 256);
    dotav<<<dim3(12500), dim3(256), 0, stream>>>(xw, gatAs + l*256, gatAd + l*256, avs, avd);
    agg  <<<dim3(12500), dim3(256), 0, stream>>>(offs, ssrc, avs, avd, xw, gatB + l*256, hgat);
    // cgn graph-norm
    hipMemsetAsync(sums, 0, 2048, stream);
    colstats  <<<dim3(256), dim3(256), 0, stream>>>(hgat, sums);
    scaleshift<<<dim3(1), dim3(256), 0, stream>>>(sums, cgnW + l*256, cgnB + l*256, cgnA + l*256, scale, shift);
    normf     <<<dim3(MPAD*64/256), dim3(256), 0, stream>>>(hgat, scale, shift, hn);
    // [y1 | y0] = [hn, xc] @ [c1;c0]^T + b  (K split 256+256)
    gemm_bf16<0,1><<<dim3(MTILES*4), dim3(256), 0, stream>>>(hn, xc, arena+OFF_CCAT + l*262144, cb + l*512, b512, 512, 512);
    // mix + gn stats, then gn graph-norm -> next-layer x
    hipMemsetAsync(sums, 0, 2048, stream);
    mixstats  <<<dim3(256), dim3(256), 0, stream>>>(b512, mask, xm, sums);
    scaleshift<<<dim3(1), dim3(256), 0, stream>>>(sums, gnW + l*256, gnB + l*256, gnA + l*256, scale, shift);
    normb     <<<dim3(MPAD*64/256), dim3(256), 0, stream>>>(xm, scale, shift, xb);
  }

  // masked pooling + final linear
  initneg<<<dim3(1), dim3(256), 0, stream>>>(pmax);
  hipMemsetAsync(psum, 0, 1024, stream);
  hipMemsetAsync(pcnt, 0, 4, stream);
  pool  <<<dim3(256), dim3(256), 0, stream>>>(xb, mask, psum, pmax, pcnt);
  finalk<<<dim3(1), dim3(256), 0, stream>>>(psum, pmax, pcnt, finW, finB, outp);
}

// Round 2
// 1502.851 us; speedup vs baseline: 1.0967x; 1.0967x over previous
//
#include <hip/hip_runtime.h>
#include <stdint.h>

#define NNODES 50000
#define NEDGES 400000
#define MPAD   50048   // 391 * 128
#define MTILES 391
#define ZRF    0.8f
#define GNEPS  1e-5f

typedef unsigned short u16;
typedef __bf16 bf16x8 __attribute__((ext_vector_type(8)));
typedef float  f32x4  __attribute__((ext_vector_type(4)));

// bf16 weight arena offsets (elements)
#define OFF_NODEW 0
#define OFF_NQM   32768
#define OFF_TCAT  163840
#define OFF_GAT   425984
#define OFF_CCAT  557056
#define W_TOTAL   1081344

__device__ __forceinline__ float b2f(u16 u){ union{uint32_t i; float f;} x; x.i=((uint32_t)u)<<16; return x.f; }
__device__ __forceinline__ u16 f2b(float f){ union{float f; uint32_t i;} x; x.f=f; uint32_t r=x.i+0x7FFFu+((x.i>>16)&1u); return (u16)(r>>16); }
__device__ __forceinline__ float lrelu(float x){ return x>0.f? x : 0.2f*x; }
__device__ __forceinline__ void atomicMaxF(float* a, float v){
  if (v>=0.f) atomicMax((int*)a, __float_as_int(v));
  else atomicMin((unsigned int*)a, (unsigned int)__float_as_int(v));
}

// ---------------- bf16 MFMA GEMM: out[M, N] = op(A[M,K(lda)] @ B[N,K]^T + bias) ----------------
// 128x128 tile, BK=64, 4 waves (2x2), 16x16x32 bf16 MFMA, XOR-swizzled LDS staging,
// XCD-chunked N-inner tile order (bijective, m204), LDS-transposed coalesced epilogue.
template<int RELU>
__global__ __launch_bounds__(256)
void gemm_bf16(const u16* __restrict__ A, int lda,
               const u16* __restrict__ B, const float* __restrict__ bias,
               u16* __restrict__ out, int ldo, int N, int K)
{
  __shared__ alignas(16) u16 smem[16896];           // Al(8192) + Bl(8192); reused as 128x132 epilogue tile
  u16* Al = smem;
  u16* Bl = smem + 8192;

  const int tid  = threadIdx.x;
  // bijective XCD chunking: hw XCD = blockIdx.x % 8 processes a contiguous logical-tile range
  const int nwg = gridDim.x;
  const int qc = nwg >> 3, rc = nwg & 7;
  const int xcd = blockIdx.x & 7, xi = blockIdx.x >> 3;
  const int lt = (xcd < rc ? xcd * (qc + 1) : rc * (qc + 1) + (xcd - rc) * qc) + xi;
  const int NT = N >> 7;
  const int bm0 = (lt / NT) * 128;   // M-panel major, N inner -> A-panel reuse within XCD
  const int bn0 = (lt % NT) * 128;

  const int KT   = K >> 6;
  const int lane = tid & 63;
  const int wv   = tid >> 6;
  const int wm   = (wv >> 1) * 64;
  const int wn   = (wv & 1) * 64;
  const int lrow = lane & 15;
  const int kgrp = (lane >> 4) * 16;   // byte offset of this lane's 8-elem k-group
  const int srow = tid >> 3;           // staging row 0..31 (+32/pass)
  const int sc   = (tid & 7) * 16;     // staging byte col

  f32x4 acc[4][4] = {};
  uint4 ar[4], br[4];

#define LOADT(ktv) do { \
    int ks = (ktv) * 64; \
    _Pragma("unroll") \
    for (int p = 0; p < 4; ++p) { \
      int rw = srow + p * 32; \
      ar[p] = *(const uint4*)(A + (size_t)(bm0 + rw) * lda + ks + (sc >> 1)); \
      br[p] = *(const uint4*)(B + (size_t)(bn0 + rw) * K   + ks + (sc >> 1)); \
    } } while (0)

  LOADT(0);
  for (int kt = 0; kt < KT; ++kt) {
    __syncthreads();
#pragma unroll
    for (int p = 0; p < 4; ++p) {
      int rw = srow + p * 32;
      int off = rw * 128 + (sc ^ ((rw & 7) << 4));
      *(uint4*)((char*)Al + off) = ar[p];
      *(uint4*)((char*)Bl + off) = br[p];
    }
    __syncthreads();
    if (kt + 1 < KT) LOADT(kt + 1);
#pragma unroll
    for (int kk = 0; kk < 2; ++kk) {
      bf16x8 af[4], bfv[4];
      int kb = kk * 64 + kgrp;
#pragma unroll
      for (int mi = 0; mi < 4; ++mi) {
        int rw = wm + mi * 16 + lrow;
        af[mi] = *(const bf16x8*)((const char*)Al + rw * 128 + (kb ^ ((rw & 7) << 4)));
      }
#pragma unroll
      for (int ni = 0; ni < 4; ++ni) {
        int rw = wn + ni * 16 + lrow;
        bfv[ni] = *(const bf16x8*)((const char*)Bl + rw * 128 + (kb ^ ((rw & 7) << 4)));
      }
#pragma unroll
      for (int mi = 0; mi < 4; ++mi)
#pragma unroll
        for (int ni = 0; ni < 4; ++ni)
          acc[mi][ni] = __builtin_amdgcn_mfma_f32_16x16x32_bf16(af[mi], bfv[ni], acc[mi][ni], 0, 0, 0);
    }
  }
#undef LOADT

  // ---- epilogue: bias/relu -> bf16 -> LDS transpose (stride 132) -> coalesced 16B stores ----
  __syncthreads();   // all LDS reads of Al/Bl done; safe to overwrite
  const int rb = (lane >> 4) * 4;   // D: col = lane&15, row = (lane>>4)*4 + reg  [m89/m91]
#pragma unroll
  for (int ni = 0; ni < 4; ++ni) {
    int coll = wn + ni * 16 + lrow;
    float bv = bias ? bias[bn0 + coll] : 0.f;
#pragma unroll
    for (int mi = 0; mi < 4; ++mi) {
      int rowl = wm + mi * 16 + rb;
#pragma unroll
      for (int r = 0; r < 4; ++r) {
        float v = acc[mi][ni][r] + bv;
        if (RELU) v = fmaxf(v, 0.f);
        smem[(rowl + r) * 132 + coll] = f2b(v);
      }
    }
  }
  __syncthreads();
#pragma unroll
  for (int p = 0; p < 8; ++p) {
    int rowl = p * 16 + (tid >> 4);
    uint4 v = *(const uint4*)&smem[rowl * 132 + (tid & 15) * 8];
    *(uint4*)&out[(size_t)(bm0 + rowl) * ldo + bn0 + (tid & 15) * 8] = v;
  }
}

// ---------------- setup / conversion kernels ----------------
__global__ void convw(const float* __restrict__ nodeW, const float* __restrict__ nqmW,
                      const float* __restrict__ t0W, const float* __restrict__ t1W,
                      const float* __restrict__ gatW, const float* __restrict__ c0W,
                      const float* __restrict__ c1W, u16* __restrict__ arena){
  int idx = blockIdx.x*256 + threadIdx.x;
  if (idx >= W_TOTAL) return;
  float v;
  if (idx < OFF_NQM) { v = nodeW[idx]; }
  else if (idx < OFF_TCAT){ int i = idx - OFF_NQM;  int l=i>>16; int r=(i>>8)&255; int k=i&255; v = nqmW[l*131072 + r*512 + k]; }
  else if (idx < OFF_GAT) { int i = idx - OFF_TCAT; int l=i>>17; int n=(i>>8)&511; int k=i&255;
                            const float* s = (n<256)? t1W : t0W; v = s[l*65536 + (n&255)*256 + k]; }
  else if (idx < OFF_CCAT){ int i = idx - OFF_GAT;  v = gatW[i]; }
  else                    { int i = idx - OFF_CCAT; int l=i>>18; int n=(i>>9)&511; int k=i&511;
                            const float* s = (n<256)? c1W : c0W; v = s[l*131072 + (n&255)*512 + k]; }
  arena[idx] = f2b(v);
}

__global__ void convxin(const float* __restrict__ x, u16* __restrict__ o){
  int idx = blockIdx.x*256 + threadIdx.x;
  if (idx >= MPAD*32) return;
  int n = idx >> 5; int c = (idx & 31)*4;
  float4 v = make_float4(0.f,0.f,0.f,0.f);
  if (n < NNODES) v = *(const float4*)&x[(size_t)n*128 + c];
  ushort4 r; r.x=f2b(v.x); r.y=f2b(v.y); r.z=f2b(v.z); r.w=f2b(v.w);
  *(ushort4*)&o[(size_t)n*128 + c] = r;
}

__global__ void biascat(const float* __restrict__ t1b, const float* __restrict__ t0b,
                        const float* __restrict__ c1b, const float* __restrict__ c0b,
                        float* __restrict__ tb, float* __restrict__ cb){
  int i = blockIdx.x*256 + threadIdx.x;
  if (i >= 2048) return;
  int which = i >> 10; int j = i & 1023; int l = j >> 9; int n = j & 511;
  const float* b1 = which ? c1b : t1b;
  const float* b0 = which ? c0b : t0b;
  float v = (n < 256) ? b1[l*256 + n] : b0[l*256 + n - 256];
  (which ? cb : tb)[l*512 + n] = v;
}

__global__ void qvk(const float* __restrict__ qemb, const float* __restrict__ W,
                    const float* __restrict__ b, float* __restrict__ qv){
  int h = threadIdx.x;
  float acc = b[h];
  for (int d = 0; d < 128; ++d) acc += qemb[d] * W[h*128 + d];
  qv[h] = fmaxf(acc, 0.f);
}

__global__ void qbk(const float* __restrict__ nqmW, const float* __restrict__ nqmB,
                    const float* __restrict__ qv, float* __restrict__ qb){
  int l = blockIdx.x, h = threadIdx.x;
  const float* wr = nqmW + l*131072 + h*512 + 256;
  float acc = nqmB[l*256 + h];
  for (int j = 0; j < 256; ++j) acc += wr[j] * qv[j];
  qb[l*256 + h] = acc;
}

// subgraph_mask marshalling detection: count nonzero bytes in first NNODES bytes.
__global__ void detmask(const unsigned char* __restrict__ mb, int* __restrict__ flag){
  __shared__ int cnt_s;
  if (threadIdx.x == 0) cnt_s = 0;
  __syncthreads();
  int c = 0;
  for (int i = threadIdx.x; i < NNODES; i += 1024) c += (mb[i] != 0);
  atomicAdd(&cnt_s, c);
  __syncthreads();
  if (threadIdx.x == 0) *flag = (cnt_s * 8 > NNODES * 3) ? 1 : 0;  // 1 => 1-byte bools
}

__global__ void maskmat(const void* __restrict__ m, const int* __restrict__ flag,
                        uint32_t* __restrict__ mask){
  int i = blockIdx.x*256 + threadIdx.x;
  if (i >= NNODES) return;
  int f = *flag;
  mask[i] = f ? (((const unsigned char*)m)[i] != 0) : (((const int*)m)[i] != 0);
}

// ---------------- edge sort (dst-sorted src list) ----------------
__global__ void hist(const int* __restrict__ dst, int* __restrict__ count){
  int i = blockIdx.x*256 + threadIdx.x;
  if (i < NEDGES) atomicAdd(&count[dst[i]], 1);
}

__global__ void scan50k(const int* __restrict__ count, int* __restrict__ offs, int* __restrict__ cursor){
  __shared__ int tmp[1024];
  __shared__ int carry_s;
  int t = threadIdx.x;
  if (t == 0) carry_s = 0;
  __syncthreads();
  for (int base = 0; base < NNODES; base += 1024) {
    int v = (base + t < NNODES) ? count[base + t] : 0;
    tmp[t] = v;
    __syncthreads();
    for (int d = 1; d < 1024; d <<= 1) {
      int add = (t >= d) ? tmp[t - d] : 0;
      __syncthreads();
      tmp[t] += add;
      __syncthreads();
    }
    int carry = carry_s;
    if (base + t < NNODES) {
      int excl = carry + tmp[t] - v;
      offs[base + t] = excl;
      cursor[base + t] = excl;
    }
    __syncthreads();
    if (t == 1023) carry_s = carry + tmp[1023];
    __syncthreads();
  }
  if (t == 0) offs[NNODES] = carry_s;
}

__global__ void scatter(const int* __restrict__ src, const int* __restrict__ dst,
                        int* __restrict__ cursor, int* __restrict__ ssrc){
  int i = blockIdx.x*256 + threadIdx.x;
  if (i >= NEDGES) return;
  int p = atomicAdd(&cursor[dst[i]], 1);
  ssrc[p] = src[i];
}

// ---------------- elementwise / graph kernels ----------------
__global__ void mixt(const u16* __restrict__ x01, const uint32_t* __restrict__ mask, u16* __restrict__ h){
  int idx = blockIdx.x*256 + threadIdx.x;
  if (idx >= MPAD*64) return;
  int n = idx >> 6; int c = (idx & 63)*4;
  float wa = 1.0f - ZRF;
  if (n < NNODES && mask[n]) wa = ZRF;
  float wb = 1.0f - wa;
  ushort4 a = *(const ushort4*)&x01[(size_t)n*512 + c];        // x1 (t1)
  ushort4 b = *(const ushort4*)&x01[(size_t)n*512 + 256 + c];  // x0 (t0)
  ushort4 r;
  r.x = f2b(wa*b2f(a.x) + wb*b2f(b.x));
  r.y = f2b(wa*b2f(a.y) + wb*b2f(b.y));
  r.z = f2b(wa*b2f(a.z) + wb*b2f(b.z));
  r.w = f2b(wa*b2f(a.w) + wb*b2f(b.w));
  *(ushort4*)&h[(size_t)n*256 + c] = r;
}

__global__ void dotav(const u16* __restrict__ xw, const float* __restrict__ asrc,
                      const float* __restrict__ adst, float* __restrict__ avs, float* __restrict__ avd){
  int wid = (blockIdx.x*256 + threadIdx.x) >> 6;
  int lane = threadIdx.x & 63;
  if (wid >= NNODES) return;
  ushort4 v = *(const ushort4*)&xw[(size_t)wid*256 + lane*4];
  float4 s4 = *(const float4*)&asrc[lane*4];
  float4 d4 = *(const float4*)&adst[lane*4];
  float x0=b2f(v.x), x1=b2f(v.y), x2=b2f(v.z), x3=b2f(v.w);
  float ps = x0*s4.x + x1*s4.y + x2*s4.z + x3*s4.w;
  float pd = x0*d4.x + x1*d4.y + x2*d4.z + x3*d4.w;
  for (int d = 32; d; d >>= 1){ ps += __shfl_xor(ps, d); pd += __shfl_xor(pd, d); }
  if (lane == 0){ avs[wid] = ps; avd[wid] = pd; }
}

// one wave per node: softmax over incoming edges (+self loop), gather-accumulate xw rows
__global__ void agg(const int* __restrict__ offs, const int* __restrict__ ssrc,
                    const float* __restrict__ avs, const float* __restrict__ avd,
                    const u16* __restrict__ xw, const float* __restrict__ gbias,
                    u16* __restrict__ out){
  int v = (blockIdx.x*256 + threadIdx.x) >> 6;
  int lane = threadIdx.x & 63;
  if (v >= NNODES) return;
  int o0 = offs[v], o1 = offs[v+1];
  float ad = avd[v];
  float slog = lrelu(avs[v] + ad);
  float m = slog;
  for (int i = o0 + lane; i < o1; i += 64) m = fmaxf(m, lrelu(avs[ssrc[i]] + ad));
  for (int d = 32; d; d >>= 1) m = fmaxf(m, __shfl_xor(m, d));
  float den = (lane == 0) ? __expf(slog - m) : 0.f;
  for (int i = o0 + lane; i < o1; i += 64) den += __expf(lrelu(avs[ssrc[i]] + ad) - m);
  for (int d = 32; d; d >>= 1) den += __shfl_xor(den, d);
  float rden = 1.0f / (den + 1e-16f);
  int c = lane*4;
  ushort4 xv = *(const ushort4*)&xw[(size_t)v*256 + c];
  float wgt = __expf(slog - m) * rden;
  float a0 = wgt*b2f(xv.x), a1 = wgt*b2f(xv.y), a2 = wgt*b2f(xv.z), a3 = wgt*b2f(xv.w);
  for (int i = o0; i < o1; ++i){
    int s = ssrc[i];
    float w = __expf(lrelu(avs[s] + ad) - m) * rden;
    ushort4 q = *(const ushort4*)&xw[(size_t)s*256 + c];
    a0 += w*b2f(q.x); a1 += w*b2f(q.y); a2 += w*b2f(q.z); a3 += w*b2f(q.w);
  }
  float4 bb = *(const float4*)&gbias[c];
  ushort4 r;
  r.x = f2b(a0 + bb.x); r.y = f2b(a1 + bb.y); r.z = f2b(a2 + bb.z); r.w = f2b(a3 + bb.w);
  *(ushort4*)&out[(size_t)v*256 + c] = r;
}

__global__ void colstats(const u16* __restrict__ x, float* __restrict__ sums){
  int c = threadIdx.x;
  float s = 0.f, q = 0.f;
  for (int n = blockIdx.x; n < NNODES; n += gridDim.x){
    float v = b2f(x[(size_t)n*256 + c]); s += v; q += v*v;
  }
  atomicAdd(&sums[c], s); atomicAdd(&sums[256 + c], q);
}

__global__ void scaleshift(const float* __restrict__ sums, const float* __restrict__ w,
                           const float* __restrict__ b, const float* __restrict__ a,
                           float* __restrict__ scale, float* __restrict__ shift){
  int c = threadIdx.x;
  const float invn = 1.0f / (float)NNODES;
  float mu  = sums[c] * invn;
  float ex2 = sums[256 + c] * invn;
  float av  = a[c];
  float var = ex2 - (2.0f*av - av*av)*mu*mu;
  float sc  = w[c] / sqrtf(var + GNEPS);
  scale[c] = sc;
  shift[c] = b[c] - sc*av*mu;
}

// x: bf16 [MPAD][256] -> o bf16 [MPAD][ldo] (writes cols 0..255)
__global__ void normf(const u16* __restrict__ x, const float* __restrict__ scale,
                      const float* __restrict__ shift, u16* __restrict__ o, int ldo){
  int idx = blockIdx.x*256 + threadIdx.x;
  if (idx >= MPAD*64) return;
  int n = idx >> 6; int c = (idx & 63)*4;
  ushort4 v = *(const ushort4*)&x[(size_t)n*256 + c];
  float4 sc = *(const float4*)&scale[c];
  float4 sh = *(const float4*)&shift[c];
  ushort4 r;
  r.x = f2b(b2f(v.x)*sc.x + sh.x); r.y = f2b(b2f(v.y)*sc.y + sh.y);
  r.z = f2b(b2f(v.z)*sc.z + sh.z); r.w = f2b(b2f(v.w)*sc.w + sh.w);
  *(ushort4*)&o[(size_t)n*ldo + c] = r;
}

__global__ void mixstats(const u16* __restrict__ y01, const uint32_t* __restrict__ mask,
                         u16* __restrict__ xm, float* __restrict__ sums){
  int c = threadIdx.x;
  float s = 0.f, q = 0.f;
  for (int n = blockIdx.x; n < MPAD; n += gridDim.x){
    float y1 = b2f(y01[(size_t)n*512 + c]);
    float y0 = b2f(y01[(size_t)n*512 + 256 + c]);
    float wa = 1.0f - ZRF;
    if (n < NNODES && mask[n]) wa = ZRF;
    float v = wa*y1 + (1.0f - wa)*y0;
    xm[(size_t)n*256 + c] = f2b(v);
    if (n < NNODES){ s += v; q += v*v; }
  }
  atomicAdd(&sums[c], s); atomicAdd(&sums[256 + c], q);
}

__global__ void initneg(float* __restrict__ pmax){ pmax[threadIdx.x] = -__builtin_inff(); }

__global__ void pool(const u16* __restrict__ x, const uint32_t* __restrict__ mask,
                     float* __restrict__ psum, float* __restrict__ pmax, int* __restrict__ pcnt){
  int c = threadIdx.x;
  float s = 0.f, mx = -__builtin_inff(); int cnt = 0;
  for (int n = blockIdx.x; n < NNODES; n += gridDim.x){
    if (mask[n]){
      float v = b2f(x[(size_t)n*256 + c]);
      s += v; mx = fmaxf(mx, v); cnt++;
    }
  }
  atomicAdd(&psum[c], s);
  atomicMaxF(&pmax[c], mx);
  if (c == 0) atomicAdd(pcnt, cnt);
}

__global__ void finalk(const float* __restrict__ psum, const float* __restrict__ pmax,
                       const int* __restrict__ pcnt, const float* __restrict__ W,
                       const float* __restrict__ b, float* __restrict__ out){
  int o = threadIdx.x;
  float cnt = fmaxf((float)(*pcnt), 1.0f);
  float inv = 1.0f / cnt;
  const float* wr = W + o*768;
  float acc = b[o];
  for (int j = 0; j < 256; ++j) acc += (psum[j]*inv) * wr[j];
  for (int j = 0; j < 256; ++j) acc += pmax[j] * wr[256 + j];
  for (int j = 0; j < 256; ++j) acc += psum[j] * wr[512 + j];
  out[o] = acc;
}

// ---------------- host orchestration ----------------
extern "C" void kernel_launch(void* const* d_in, const int* in_sizes, int n_in,
                              void* d_out, int out_size, void* d_ws, size_t ws_size,
                              hipStream_t stream)
{
  (void)in_sizes; (void)n_in; (void)out_size; (void)ws_size;
  const float* x_    = (const float*)d_in[0];
  const int*   eidx  = (const int*)  d_in[1];
  const float* qemb  = (const float*)d_in[3];
  const void*  mraw  =               d_in[4];
  const float* nodeW = (const float*)d_in[5];
  const float* nodeB = (const float*)d_in[6];
  const float* qinW  = (const float*)d_in[9];
  const float* qinB  = (const float*)d_in[10];
  const float* nqmW  = (const float*)d_in[11];
  const float* nqmB  = (const float*)d_in[12];
  const float* t0W   = (const float*)d_in[15];
  const float* t0B   = (const float*)d_in[16];
  const float* t1W   = (const float*)d_in[17];
  const float* t1B   = (const float*)d_in[18];
  const float* gatW  = (const float*)d_in[19];
  const float* gatAs = (const float*)d_in[20];
  const float* gatAd = (const float*)d_in[21];
  const float* gatB  = (const float*)d_in[22];
  const float* cgnW  = (const float*)d_in[23];
  const float* cgnB  = (const float*)d_in[24];
  const float* cgnA  = (const float*)d_in[25];
  const float* c0W   = (const float*)d_in[26];
  const float* c0B   = (const float*)d_in[27];
  const float* c1W   = (const float*)d_in[28];
  const float* c1B   = (const float*)d_in[29];
  const float* gnW   = (const float*)d_in[30];
  const float* gnB   = (const float*)d_in[31];
  const float* gnA   = (const float*)d_in[32];
  const float* finW  = (const float*)d_in[33];
  const float* finB  = (const float*)d_in[34];
  float* outp = (float*)d_out;

  char* p = (char*)d_ws;
  auto alloc = [&](size_t b)->char*{ char* r = p; p += (b + 511) & ~(size_t)511; return r; };
  u16*      arena = (u16*)     alloc((size_t)W_TOTAL*2);
  float*    tb    = (float*)   alloc(1024*4);
  float*    cb    = (float*)   alloc(1024*4);
  float*    qv    = (float*)   alloc(256*4);
  float*    qb    = (float*)   alloc(512*4);
  float*    scale = (float*)   alloc(256*4);
  float*    shift = (float*)   alloc(256*4);
  float*    sums  = (float*)   alloc(512*4);
  float*    psum  = (float*)   alloc(256*4);
  float*    pmax  = (float*)   alloc(256*4);
  int*      pcnt  = (int*)     alloc(256);
  int*      flag  = (int*)     alloc(256);
  uint32_t* mask  = (uint32_t*)alloc((size_t)NNODES*4);
  int*      count = (int*)     alloc((size_t)NNODES*4);
  int*      offs  = (int*)     alloc((size_t)(NNODES+1)*4);
  int*      cursor= (int*)     alloc((size_t)NNODES*4);
  int*      ssrc  = (int*)     alloc((size_t)NEDGES*4);
  float*    avs   = (float*)   alloc((size_t)NNODES*4);
  float*    avd   = (float*)   alloc((size_t)NNODES*4);
  u16*      xin   = (u16*)     alloc((size_t)MPAD*128*2);
  u16*      xb    = (u16*)     alloc((size_t)MPAD*256*2);
  u16*      hxc   = (u16*)     alloc((size_t)MPAD*512*2);  // cols 0-255: hn, cols 256-511: xc
  u16*      hb    = (u16*)     alloc((size_t)MPAD*256*2);
  u16*      xw    = (u16*)     alloc((size_t)MPAD*256*2);
  u16*      xm    = (u16*)     alloc((size_t)MPAD*256*2);
  u16*      b512  = (u16*)     alloc((size_t)MPAD*512*2);
  u16*      hgat  = (u16*)     alloc((size_t)MPAD*256*2);

  const int* esrc = eidx;
  const int* edst = eidx + NEDGES;

  // setup: weight conversion, q-branch, mask decode, dst-sorted edge list
  convw  <<<dim3((W_TOTAL+255)/256), dim3(256), 0, stream>>>(nodeW, nqmW, t0W, t1W, gatW, c0W, c1W, arena);
  convxin<<<dim3(MPAD*32/256), dim3(256), 0, stream>>>(x_, xin);
  biascat<<<dim3(8), dim3(256), 0, stream>>>(t1B, t0B, c1B, c0B, tb, cb);
  qvk    <<<dim3(1), dim3(256), 0, stream>>>(qemb, qinW, qinB, qv);
  qbk    <<<dim3(2), dim3(256), 0, stream>>>(nqmW, nqmB, qv, qb);
  detmask<<<dim3(1), dim3(1024), 0, stream>>>((const unsigned char*)mraw, flag);
  maskmat<<<dim3((NNODES+255)/256), dim3(256), 0, stream>>>(mraw, flag, mask);
  hipMemsetAsync(count, 0, (size_t)NNODES*4, stream);
  hist   <<<dim3((NEDGES+255)/256), dim3(256), 0, stream>>>(edst, count);
  scan50k<<<dim3(1), dim3(1024), 0, stream>>>(count, offs, cursor);
  scatter<<<dim3((NEDGES+255)/256), dim3(256), 0, stream>>>(esrc, edst, cursor, ssrc);

  // x = relu(x_ @ node_in_W^T + b)
  gemm_bf16<1><<<dim3(MTILES*2), dim3(256), 0, stream>>>(xin, 128, arena+OFF_NODEW, nodeB, xb, 256, 256, 128);

  for (int l = 0; l < 2; ++l) {
    // xc = relu(x @ nqm_W[:, :H]^T + (qb: q-part + bias))  -> hxc cols 256-511
    gemm_bf16<1><<<dim3(MTILES*2), dim3(256), 0, stream>>>(xb, 256, arena+OFF_NQM + l*65536, qb + l*256, hxc + 256, 512, 256, 256);
    // [x1 | x0] = relu(xc @ [t1;t0]^T + b)
    gemm_bf16<1><<<dim3(MTILES*4), dim3(256), 0, stream>>>(hxc + 256, 512, arena+OFF_TCAT + l*131072, tb + l*512, b512, 512, 512, 256);
    mixt<<<dim3(MPAD*64/256), dim3(256), 0, stream>>>(b512, mask, hb);
    // xw = h @ gat_W^T
    gemm_bf16<0><<<dim3(MTILES*2), dim3(256), 0, stream>>>(hb, 256, arena+OFF_GAT + l*65536, nullptr, xw, 256, 256, 256);
    dotav<<<dim3(12500), dim3(256), 0, stream>>>(xw, gatAs + l*256, gatAd + l*256, avs, avd);
    agg  <<<dim3(12500), dim3(256), 0, stream>>>(offs, ssrc, avs, avd, xw, gatB + l*256, hgat);
    // cgn graph-norm -> hxc cols 0-255
    hipMemsetAsync(sums, 0, 2048, stream);
    colstats  <<<dim3(256), dim3(256), 0, stream>>>(hgat, sums);
    scaleshift<<<dim3(1), dim3(256), 0, stream>>>(sums, cgnW + l*256, cgnB + l*256, cgnA + l*256, scale, shift);
    normf     <<<dim3(MPAD*64/256), dim3(256), 0, stream>>>(hgat, scale, shift, hxc, 512);
    // [y1 | y0] = [hn, xc] @ [c1;c0]^T + b
    gemm_bf16<0><<<dim3(MTILES*4), dim3(256), 0, stream>>>(hxc, 512, arena+OFF_CCAT + l*262144, cb + l*512, b512, 512, 512, 512);
    // mix + gn stats, then gn graph-norm -> next-layer x
    hipMemsetAsync(sums, 0, 2048, stream);
    mixstats  <<<dim3(256), dim3(256), 0, stream>>>(b512, mask, xm, sums);
    scaleshift<<<dim3(1), dim3(256), 0, stream>>>(sums, gnW + l*256, gnB + l*256, gnA + l*256, scale, shift);
    normf     <<<dim3(MPAD*64/256), dim3(256), 0, stream>>>(xm, scale, shift, xb, 256);
  }

  // masked pooling + final linear
  initneg<<<dim3(1), dim3(256), 0, stream>>>(pmax);
  hipMemsetAsync(psum, 0, 1024, stream);
  hipMemsetAsync(pcnt, 0, 4, stream);
  pool  <<<dim3(256), dim3(256), 0, stream>>>(xb, mask, psum, pmax, pcnt);
  finalk<<<dim3(1), dim3(256), 0, stream>>>(psum, pmax, pcnt, finW, finB, outp);
}

// Round 3
// 1060.420 us; speedup vs baseline: 1.5543x; 1.4172x over previous
//
#include <hip/hip_runtime.h>
#include <stdint.h>

#define NNODES 50000
#define NEDGES 400000
#define MPAD   50048   // 391 * 128
#define MTILES 391
#define ZRF    0.8f
#define GNEPS  1e-5f

typedef unsigned short u16;
typedef __bf16 bf16x8 __attribute__((ext_vector_type(8)));
typedef float  f32x4  __attribute__((ext_vector_type(4)));

// bf16 weight arena offsets (elements)
#define OFF_NODEW 0
#define OFF_NQM   32768
#define OFF_TCAT  163840
#define OFF_GAT   425984
#define OFF_CCAT  557056
#define W_TOTAL   1081344

__device__ __forceinline__ float b2f(u16 u){ union{uint32_t i; float f;} x; x.i=((uint32_t)u)<<16; return x.f; }
__device__ __forceinline__ u16 f2b(float f){ union{float f; uint32_t i;} x; x.f=f; uint32_t r=x.i+0x7FFFu+((x.i>>16)&1u); return (u16)(r>>16); }
__device__ __forceinline__ float lrelu(float x){ return x>0.f? x : 0.2f*x; }
__device__ __forceinline__ void atomicMaxF(float* a, float v){
  if (v>=0.f) atomicMax((int*)a, __float_as_int(v));
  else atomicMin((unsigned int*)a, (unsigned int)__float_as_int(v));
}

// ---------------- bf16 MFMA GEMM ----------------
// MODE 0: out[M,N] = op(A @ B^T + bias), N = NT*128 tiles.
// MODE 1: dual-half (B rows [bn,bn+128) and [256+bn,...)), relu both, mix by mask -> out[M,256].
// MODE 2: dual-half, no relu, mix by mask -> out[M,256], + masked column stats atomics.
// 128-row M tile, BK=64, 4 waves, 16x16x32 MFMA, XOR-swizzled LDS, XCD-chunked, LDS-transposed epilogue.
template<int MODE, int RELU>
__global__ __launch_bounds__(256, 2)
void gemm(const u16* __restrict__ A0, const u16* __restrict__ A1, int ldA,
          const u16* __restrict__ B, const float* __restrict__ bias,
          u16* __restrict__ out, int ldo, int NT, int K,
          const uint32_t* __restrict__ mask, float* __restrict__ sums)
{
  __shared__ alignas(16) u16 smem[MODE ? 24576 : 16896];
  __shared__ float was[128];
  __shared__ float val[128];
  u16* Al  = smem;
  u16* Bl0 = smem + 8192;
  u16* Bl1 = smem + 16384;

  const int tid  = threadIdx.x;
  const int nwg = gridDim.x;
  const int qc = nwg >> 3, rc = nwg & 7;
  const int xcd = blockIdx.x & 7, xi = blockIdx.x >> 3;
  const int lt = (xcd < rc ? xcd * (qc + 1) : rc * (qc + 1) + (xcd - rc) * qc) + xi;
  const int bm0 = (lt / NT) * 128;
  const int bn0 = (lt % NT) * 128;

  if (MODE && tid < 128) {
    int gr = bm0 + tid;
    int mk = (gr < NNODES) ? (mask[gr] != 0) : 0;
    was[tid] = mk ? ZRF : (1.0f - ZRF);
    val[tid] = (gr < NNODES) ? 1.0f : 0.0f;
  }

  const int KT   = K >> 6;
  const int lane = tid & 63;
  const int wv   = tid >> 6;
  const int wm   = (wv >> 1) * 64;
  const int wn   = (wv & 1) * 64;
  const int lrow = lane & 15;
  const int kgrp = (lane >> 4) * 16;
  const int srow = tid >> 3;
  const int sc   = (tid & 7) * 16;

  f32x4 acc[MODE ? 2 : 1][4][4] = {};
  uint4 ar[4], b1r[4], b0r[4];

#define LOADT(ktv) do { \
    int ks = (ktv) * 64; \
    const u16* Ap; int kloc, ldaa; \
    if (A1 && ks >= 256) { Ap = A1; kloc = ks - 256; ldaa = 256; } \
    else { Ap = A0; kloc = ks; ldaa = ldA; } \
    _Pragma("unroll") \
    for (int p = 0; p < 4; ++p) { \
      int rw = srow + p * 32; \
      ar[p]  = *(const uint4*)(Ap + (size_t)(bm0 + rw) * ldaa + kloc + (sc >> 1)); \
      b1r[p] = *(const uint4*)(B  + (size_t)(bn0 + rw) * K + ks + (sc >> 1)); \
      if (MODE) b0r[p] = *(const uint4*)(B + (size_t)(256 + bn0 + rw) * K + ks + (sc >> 1)); \
    } } while (0)

  LOADT(0);
  for (int kt = 0; kt < KT; ++kt) {
    __syncthreads();
#pragma unroll
    for (int p = 0; p < 4; ++p) {
      int rw = srow + p * 32;
      int off = rw * 128 + (sc ^ ((rw & 7) << 4));
      *(uint4*)((char*)Al  + off) = ar[p];
      *(uint4*)((char*)Bl0 + off) = b1r[p];
      if (MODE) *(uint4*)((char*)Bl1 + off) = b0r[p];
    }
    __syncthreads();
    if (kt + 1 < KT) LOADT(kt + 1);
#pragma unroll
    for (int kk = 0; kk < 2; ++kk) {
      bf16x8 af[4], bfv[4];
      int kb = kk * 64 + kgrp;
#pragma unroll
      for (int mi = 0; mi < 4; ++mi) {
        int rw = wm + mi * 16 + lrow;
        af[mi] = *(const bf16x8*)((const char*)Al + rw * 128 + (kb ^ ((rw & 7) << 4)));
      }
#pragma unroll
      for (int ni = 0; ni < 4; ++ni) {
        int rw = wn + ni * 16 + lrow;
        bfv[ni] = *(const bf16x8*)((const char*)Bl0 + rw * 128 + (kb ^ ((rw & 7) << 4)));
      }
#pragma unroll
      for (int mi = 0; mi < 4; ++mi)
#pragma unroll
        for (int ni = 0; ni < 4; ++ni)
          acc[0][mi][ni] = __builtin_amdgcn_mfma_f32_16x16x32_bf16(af[mi], bfv[ni], acc[0][mi][ni], 0, 0, 0);
      if (MODE) {
#pragma unroll
        for (int ni = 0; ni < 4; ++ni) {
          int rw = wn + ni * 16 + lrow;
          bfv[ni] = *(const bf16x8*)((const char*)Bl1 + rw * 128 + (kb ^ ((rw & 7) << 4)));
        }
#pragma unroll
        for (int mi = 0; mi < 4; ++mi)
#pragma unroll
          for (int ni = 0; ni < 4; ++ni)
            acc[1][mi][ni] = __builtin_amdgcn_mfma_f32_16x16x32_bf16(af[mi], bfv[ni], acc[1][mi][ni], 0, 0, 0);
      }
    }
  }
#undef LOADT

  // ---- epilogue ----
  __syncthreads();
  const int rb = (lane >> 4) * 4;   // D: col = lane&15, row = (lane>>4)*4 + reg
  float s_acc[4] = {0,0,0,0}, q_acc[4] = {0,0,0,0};
#pragma unroll
  for (int ni = 0; ni < 4; ++ni) {
    int coll = wn + ni * 16 + lrow;
    float b1 = bias ? bias[bn0 + coll] : 0.f;
    float b0 = (MODE && bias) ? bias[256 + bn0 + coll] : 0.f;
#pragma unroll
    for (int mi = 0; mi < 4; ++mi) {
      int rowl = wm + mi * 16 + rb;
#pragma unroll
      for (int r = 0; r < 4; ++r) {
        float v;
        if (MODE) {
          float v1 = acc[0][mi][ni][r] + b1;
          float v0 = acc[1][mi][ni][r] + b0;
          if (RELU) { v1 = fmaxf(v1, 0.f); v0 = fmaxf(v0, 0.f); }
          float wa = was[rowl + r];
          v = wa * v1 + (1.0f - wa) * v0;
          if (MODE == 2) {
            float vl = val[rowl + r];
            s_acc[ni] += v * vl;
            q_acc[ni] += v * v * vl;
          }
        } else {
          v = acc[0][mi][ni][r] + b1;
          if (RELU) v = fmaxf(v, 0.f);
        }
        smem[(rowl + r) * 132 + coll] = f2b(v);
      }
    }
  }
  __syncthreads();
#pragma unroll
  for (int p = 0; p < 8; ++p) {
    int rowl = p * 16 + (tid >> 4);
    uint4 v = *(const uint4*)&smem[rowl * 132 + (tid & 15) * 8];
    *(uint4*)&out[(size_t)(bm0 + rowl) * ldo + bn0 + (tid & 15) * 8] = v;
  }
  if (MODE == 2) {
#pragma unroll
    for (int ni = 0; ni < 4; ++ni) {
      s_acc[ni] += __shfl_xor(s_acc[ni], 16); s_acc[ni] += __shfl_xor(s_acc[ni], 32);
      q_acc[ni] += __shfl_xor(q_acc[ni], 16); q_acc[ni] += __shfl_xor(q_acc[ni], 32);
    }
    if (lane < 16) {
#pragma unroll
      for (int ni = 0; ni < 4; ++ni) {
        int gc = bn0 + wn + ni * 16 + lane;
        atomicAdd(&sums[gc], s_acc[ni]);
        atomicAdd(&sums[256 + gc], q_acc[ni]);
      }
    }
  }
}

// ---------------- weight fold: Wd = Ws .* scale(cols<foldK), bd = bs + Ws[:, :foldK] @ shift ----------------
__global__ void foldw(const u16* __restrict__ Ws, const float* __restrict__ bs,
                      const float* __restrict__ scale, const float* __restrict__ shift,
                      int K, u16* __restrict__ Wd, float* __restrict__ bd){
  int n = blockIdx.x, t = threadIdx.x;
  float bacc = 0.f;
  for (int k = t; k < K; k += 256) {
    float w = b2f(Ws[(size_t)n * K + k]);
    if (k < 256) { bacc += w * shift[k]; w *= scale[k]; }
    Wd[(size_t)n * K + k] = f2b(w);
  }
  for (int d = 32; d; d >>= 1) bacc += __shfl_xor(bacc, d);
  __shared__ float red[4];
  if ((t & 63) == 0) red[t >> 6] = bacc;
  __syncthreads();
  if (t == 0) bd[n] = bs[n] + red[0] + red[1] + red[2] + red[3];
}

// ---------------- setup / conversion kernels ----------------
__global__ void convw(const float* __restrict__ nodeW, const float* __restrict__ nqmW,
                      const float* __restrict__ t0W, const float* __restrict__ t1W,
                      const float* __restrict__ gatW, const float* __restrict__ c0W,
                      const float* __restrict__ c1W, u16* __restrict__ arena){
  int idx = blockIdx.x*256 + threadIdx.x;
  if (idx >= W_TOTAL) return;
  float v;
  if (idx < OFF_NQM) { v = nodeW[idx]; }
  else if (idx < OFF_TCAT){ int i = idx - OFF_NQM;  int l=i>>16; int r=(i>>8)&255; int k=i&255; v = nqmW[l*131072 + r*512 + k]; }
  else if (idx < OFF_GAT) { int i = idx - OFF_TCAT; int l=i>>17; int n=(i>>8)&511; int k=i&255;
                            const float* s = (n<256)? t1W : t0W; v = s[l*65536 + (n&255)*256 + k]; }
  else if (idx < OFF_CCAT){ int i = idx - OFF_GAT;  v = gatW[i]; }
  else                    { int i = idx - OFF_CCAT; int l=i>>18; int n=(i>>9)&511; int k=i&511;
                            const float* s = (n<256)? c1W : c0W; v = s[l*131072 + (n&255)*512 + k]; }
  arena[idx] = f2b(v);
}

__global__ void convxin(const float* __restrict__ x, u16* __restrict__ o){
  int idx = blockIdx.x*256 + threadIdx.x;
  if (idx >= MPAD*32) return;
  int n = idx >> 5; int c = (idx & 31)*4;
  float4 v = make_float4(0.f,0.f,0.f,0.f);
  if (n < NNODES) v = *(const float4*)&x[(size_t)n*128 + c];
  ushort4 r; r.x=f2b(v.x); r.y=f2b(v.y); r.z=f2b(v.z); r.w=f2b(v.w);
  *(ushort4*)&o[(size_t)n*128 + c] = r;
}

__global__ void biascat(const float* __restrict__ t1b, const float* __restrict__ t0b,
                        const float* __restrict__ c1b, const float* __restrict__ c0b,
                        float* __restrict__ tb, float* __restrict__ cb){
  int i = blockIdx.x*256 + threadIdx.x;
  if (i >= 2048) return;
  int which = i >> 10; int j = i & 1023; int l = j >> 9; int n = j & 511;
  const float* b1 = which ? c1b : t1b;
  const float* b0 = which ? c0b : t0b;
  float v = (n < 256) ? b1[l*256 + n] : b0[l*256 + n - 256];
  (which ? cb : tb)[l*512 + n] = v;
}

__global__ void qvk(const float* __restrict__ qemb, const float* __restrict__ W,
                    const float* __restrict__ b, float* __restrict__ qv){
  int h = threadIdx.x;
  float acc = b[h];
  for (int d = 0; d < 128; ++d) acc += qemb[d] * W[h*128 + d];
  qv[h] = fmaxf(acc, 0.f);
}

__global__ void qbk(const float* __restrict__ nqmW, const float* __restrict__ nqmB,
                    const float* __restrict__ qv, float* __restrict__ qb){
  int l = blockIdx.x, h = threadIdx.x;
  const float* wr = nqmW + l*131072 + h*512 + 256;
  float acc = nqmB[l*256 + h];
  for (int j = 0; j < 256; ++j) acc += wr[j] * qv[j];
  qb[l*256 + h] = acc;
}

__global__ void detmask(const unsigned char* __restrict__ mb, int* __restrict__ flag){
  __shared__ int cnt_s;
  if (threadIdx.x == 0) cnt_s = 0;
  __syncthreads();
  int c = 0;
  for (int i = threadIdx.x; i < NNODES; i += 1024) c += (mb[i] != 0);
  atomicAdd(&cnt_s, c);
  __syncthreads();
  if (threadIdx.x == 0) *flag = (cnt_s * 8 > NNODES * 3) ? 1 : 0;
}

__global__ void maskmat(const void* __restrict__ m, const int* __restrict__ flag,
                        uint32_t* __restrict__ mask){
  int i = blockIdx.x*256 + threadIdx.x;
  if (i >= NNODES) return;
  int f = *flag;
  mask[i] = f ? (((const unsigned char*)m)[i] != 0) : (((const int*)m)[i] != 0);
}

// ---------------- edge sort (dst-sorted src list) ----------------
__global__ void hist(const int* __restrict__ dst, int* __restrict__ count){
  int i = blockIdx.x*256 + threadIdx.x;
  if (i < NEDGES) atomicAdd(&count[dst[i]], 1);
}

__global__ void scan50k(const int* __restrict__ count, int* __restrict__ offs, int* __restrict__ cursor){
  __shared__ int tmp[1024];
  __shared__ int carry_s;
  int t = threadIdx.x;
  if (t == 0) carry_s = 0;
  __syncthreads();
  for (int base = 0; base < NNODES; base += 1024) {
    int v = (base + t < NNODES) ? count[base + t] : 0;
    tmp[t] = v;
    __syncthreads();
    for (int d = 1; d < 1024; d <<= 1) {
      int add = (t >= d) ? tmp[t - d] : 0;
      __syncthreads();
      tmp[t] += add;
      __syncthreads();
    }
    int carry = carry_s;
    if (base + t < NNODES) {
      int excl = carry + tmp[t] - v;
      offs[base + t] = excl;
      cursor[base + t] = excl;
    }
    __syncthreads();
    if (t == 1023) carry_s = carry + tmp[1023];
    __syncthreads();
  }
  if (t == 0) offs[NNODES] = carry_s;
}

__global__ void scatter(const int* __restrict__ src, const int* __restrict__ dst,
                        int* __restrict__ cursor, int* __restrict__ ssrc){
  int i = blockIdx.x*256 + threadIdx.x;
  if (i >= NEDGES) return;
  int p = atomicAdd(&cursor[dst[i]], 1);
  ssrc[p] = src[i];
}

// ---------------- graph kernels ----------------
__global__ void dotav(const u16* __restrict__ xw, const float* __restrict__ asrc,
                      const float* __restrict__ adst, float* __restrict__ avs, float* __restrict__ avd){
  int wid = (blockIdx.x*256 + threadIdx.x) >> 6;
  int lane = threadIdx.x & 63;
  if (wid >= NNODES) return;
  ushort4 v = *(const ushort4*)&xw[(size_t)wid*256 + lane*4];
  float4 s4 = *(const float4*)&asrc[lane*4];
  float4 d4 = *(const float4*)&adst[lane*4];
  float x0=b2f(v.x), x1=b2f(v.y), x2=b2f(v.z), x3=b2f(v.w);
  float ps = x0*s4.x + x1*s4.y + x2*s4.z + x3*s4.w;
  float pd = x0*d4.x + x1*d4.y + x2*d4.z + x3*d4.w;
  for (int d = 32; d; d >>= 1){ ps += __shfl_xor(ps, d); pd += __shfl_xor(pd, d); }
  if (lane == 0){ avs[wid] = ps; avd[wid] = pd; }
}

__global__ void agg(const int* __restrict__ offs, const int* __restrict__ ssrc,
                    const float* __restrict__ avs, const float* __restrict__ avd,
                    const u16* __restrict__ xw, const float* __restrict__ gbias,
                    u16* __restrict__ out){
  int v = (blockIdx.x*256 + threadIdx.x) >> 6;
  int lane = threadIdx.x & 63;
  if (v >= NNODES) return;
  int o0 = offs[v], o1 = offs[v+1];
  float ad = avd[v];
  float slog = lrelu(avs[v] + ad);
  float m = slog;
  for (int i = o0 + lane; i < o1; i += 64) m = fmaxf(m, lrelu(avs[ssrc[i]] + ad));
  for (int d = 32; d; d >>= 1) m = fmaxf(m, __shfl_xor(m, d));
  float den = (lane == 0) ? __expf(slog - m) : 0.f;
  for (int i = o0 + lane; i < o1; i += 64) den += __expf(lrelu(avs[ssrc[i]] + ad) - m);
  for (int d = 32; d; d >>= 1) den += __shfl_xor(den, d);
  float rden = 1.0f / (den + 1e-16f);
  int c = lane*4;
  ushort4 xv = *(const ushort4*)&xw[(size_t)v*256 + c];
  float wgt = __expf(slog - m) * rden;
  float a0 = wgt*b2f(xv.x), a1 = wgt*b2f(xv.y), a2 = wgt*b2f(xv.z), a3 = wgt*b2f(xv.w);
  for (int i = o0; i < o1; ++i){
    int s = ssrc[i];
    float w = __expf(lrelu(avs[s] + ad) - m) * rden;
    ushort4 q = *(const ushort4*)&xw[(size_t)s*256 + c];
    a0 += w*b2f(q.x); a1 += w*b2f(q.y); a2 += w*b2f(q.z); a3 += w*b2f(q.w);
  }
  float4 bb = *(const float4*)&gbias[c];
  ushort4 r;
  r.x = f2b(a0 + bb.x); r.y = f2b(a1 + bb.y); r.z = f2b(a2 + bb.z); r.w = f2b(a3 + bb.w);
  *(ushort4*)&out[(size_t)v*256 + c] = r;
}

__global__ void colstats(const u16* __restrict__ x, float* __restrict__ sums){
  int c = threadIdx.x;
  float s = 0.f, q = 0.f;
  for (int n = blockIdx.x; n < NNODES; n += gridDim.x){
    float v = b2f(x[(size_t)n*256 + c]); s += v; q += v*v;
  }
  atomicAdd(&sums[c], s); atomicAdd(&sums[256 + c], q);
}

__global__ void scaleshift(const float* __restrict__ sums, const float* __restrict__ w,
                           const float* __restrict__ b, const float* __restrict__ a,
                           float* __restrict__ scale, float* __restrict__ shift){
  int c = threadIdx.x;
  const float invn = 1.0f / (float)NNODES;
  float mu  = sums[c] * invn;
  float ex2 = sums[256 + c] * invn;
  float av  = a[c];
  float var = ex2 - (2.0f*av - av*av)*mu*mu;
  float sc  = w[c] / sqrtf(var + GNEPS);
  scale[c] = sc;
  shift[c] = b[c] - sc*av*mu;
}

__global__ void initneg(float* __restrict__ pmax){ pmax[threadIdx.x] = -__builtin_inff(); }

// pool over affine(x): v = b2f(x)*scale + shift, masked
__global__ void pool(const u16* __restrict__ x, const uint32_t* __restrict__ mask,
                     const float* __restrict__ scale, const float* __restrict__ shift,
                     float* __restrict__ psum, float* __restrict__ pmax, int* __restrict__ pcnt){
  int c = threadIdx.x;
  float sc = scale[c], sh = shift[c];
  float s = 0.f, mx = -__builtin_inff(); int cnt = 0;
  for (int n = blockIdx.x; n < NNODES; n += gridDim.x){
    if (mask[n]){
      float v = b2f(x[(size_t)n*256 + c]) * sc + sh;
      s += v; mx = fmaxf(mx, v); cnt++;
    }
  }
  atomicAdd(&psum[c], s);
  atomicMaxF(&pmax[c], mx);
  if (c == 0) atomicAdd(pcnt, cnt);
}

__global__ void finalk(const float* __restrict__ psum, const float* __restrict__ pmax,
                       const int* __restrict__ pcnt, const float* __restrict__ W,
                       const float* __restrict__ b, float* __restrict__ out){
  int o = threadIdx.x;
  float cnt = fmaxf((float)(*pcnt), 1.0f);
  float inv = 1.0f / cnt;
  const float* wr = W + o*768;
  float acc = b[o];
  for (int j = 0; j < 256; ++j) acc += (psum[j]*inv) * wr[j];
  for (int j = 0; j < 256; ++j) acc += pmax[j] * wr[256 + j];
  for (int j = 0; j < 256; ++j) acc += psum[j] * wr[512 + j];
  out[o] = acc;
}

// ---------------- host orchestration ----------------
extern "C" void kernel_launch(void* const* d_in, const int* in_sizes, int n_in,
                              void* d_out, int out_size, void* d_ws, size_t ws_size,
                              hipStream_t stream)
{
  (void)in_sizes; (void)n_in; (void)out_size; (void)ws_size;
  const float* x_    = (const float*)d_in[0];
  const int*   eidx  = (const int*)  d_in[1];
  const float* qemb  = (const float*)d_in[3];
  const void*  mraw  =               d_in[4];
  const float* nodeW = (const float*)d_in[5];
  const float* nodeB = (const float*)d_in[6];
  const float* qinW  = (const float*)d_in[9];
  const float* qinB  = (const float*)d_in[10];
  const float* nqmW  = (const float*)d_in[11];
  const float* nqmB  = (const float*)d_in[12];
  const float* t0B   = (const float*)d_in[16];
  const float* t1B   = (const float*)d_in[18];
  const float* gatAs = (const float*)d_in[20];
  const float* gatAd = (const float*)d_in[21];
  const float* gatB  = (const float*)d_in[22];
  const float* cgnW  = (const float*)d_in[23];
  const float* cgnB  = (const float*)d_in[24];
  const float* cgnA  = (const float*)d_in[25];
  const float* c0B   = (const float*)d_in[27];
  const float* c1B   = (const float*)d_in[29];
  const float* gnW   = (const float*)d_in[30];
  const float* gnB   = (const float*)d_in[31];
  const float* gnA   = (const float*)d_in[32];
  const float* finW  = (const float*)d_in[33];
  const float* finB  = (const float*)d_in[34];
  const float* t0W   = (const float*)d_in[15];
  const float* t1W   = (const float*)d_in[17];
  const float* gatW  = (const float*)d_in[19];
  const float* c0W   = (const float*)d_in[26];
  const float* c1W   = (const float*)d_in[28];
  float* outp = (float*)d_out;

  char* p = (char*)d_ws;
  auto alloc = [&](size_t b)->char*{ char* r = p; p += (b + 511) & ~(size_t)511; return r; };
  u16*      arena = (u16*)     alloc((size_t)W_TOTAL*2);
  u16*      wtc   = (u16*)     alloc((size_t)512*512*2);
  u16*      wtn   = (u16*)     alloc((size_t)256*256*2);
  float*    btc   = (float*)   alloc(512*4);
  float*    qbt   = (float*)   alloc(256*4);
  float*    tb    = (float*)   alloc(1024*4);
  float*    cb    = (float*)   alloc(1024*4);
  float*    qv    = (float*)   alloc(256*4);
  float*    qb    = (float*)   alloc(512*4);
  float*    scaleC= (float*)   alloc(256*4);
  float*    shiftC= (float*)   alloc(256*4);
  float*    scaleG= (float*)   alloc(256*4);
  float*    shiftG= (float*)   alloc(256*4);
  float*    sums  = (float*)   alloc(512*4);
  float*    psum  = (float*)   alloc(256*4);
  float*    pmax  = (float*)   alloc(256*4);
  int*      pcnt  = (int*)     alloc(256);
  int*      flag  = (int*)     alloc(256);
  uint32_t* mask  = (uint32_t*)alloc((size_t)NNODES*4);
  int*      count = (int*)     alloc((size_t)NNODES*4);
  int*      offs  = (int*)     alloc((size_t)(NNODES+1)*4);
  int*      cursor= (int*)     alloc((size_t)NNODES*4);
  int*      ssrc  = (int*)     alloc((size_t)NEDGES*4);
  float*    avs   = (float*)   alloc((size_t)NNODES*4);
  float*    avd   = (float*)   alloc((size_t)NNODES*4);
  u16*      xin   = (u16*)     alloc((size_t)MPAD*128*2);
  u16*      xb    = (u16*)     alloc((size_t)MPAD*256*2);
  u16*      xc    = (u16*)     alloc((size_t)MPAD*256*2);
  u16*      hb    = (u16*)     alloc((size_t)MPAD*256*2);
  u16*      xw    = (u16*)     alloc((size_t)MPAD*256*2);
  u16*      hgat  = (u16*)     alloc((size_t)MPAD*256*2);
  u16*      xm    = (u16*)     alloc((size_t)MPAD*256*2);

  const int* esrc = eidx;
  const int* edst = eidx + NEDGES;

  // setup
  convw  <<<dim3((W_TOTAL+255)/256), dim3(256), 0, stream>>>(nodeW, nqmW, t0W, t1W, gatW, c0W, c1W, arena);
  convxin<<<dim3(MPAD*32/256), dim3(256), 0, stream>>>(x_, xin);
  biascat<<<dim3(8), dim3(256), 0, stream>>>(t1B, t0B, c1B, c0B, tb, cb);
  qvk    <<<dim3(1), dim3(256), 0, stream>>>(qemb, qinW, qinB, qv);
  qbk    <<<dim3(2), dim3(256), 0, stream>>>(nqmW, nqmB, qv, qb);
  detmask<<<dim3(1), dim3(1024), 0, stream>>>((const unsigned char*)mraw, flag);
  maskmat<<<dim3((NNODES+255)/256), dim3(256), 0, stream>>>(mraw, flag, mask);
  hipMemsetAsync(count, 0, (size_t)NNODES*4, stream);
  hist   <<<dim3((NEDGES+255)/256), dim3(256), 0, stream>>>(edst, count);
  scan50k<<<dim3(1), dim3(1024), 0, stream>>>(count, offs, cursor);
  scatter<<<dim3((NEDGES+255)/256), dim3(256), 0, stream>>>(esrc, edst, cursor, ssrc);

  // x = relu(x_ @ node_in_W^T + b)
  gemm<0,1><<<dim3(MTILES*2), dim3(256), 0, stream>>>(xin, nullptr, 128, arena+OFF_NODEW, nodeB, xb, 256, 2, 128, nullptr, nullptr);

  for (int l = 0; l < 2; ++l) {
    // xc = relu(x @ Wnqm^T + qbias)   (layer1: gn-folded weights, xm input)
    if (l == 0)
      gemm<0,1><<<dim3(MTILES*2), dim3(256), 0, stream>>>(xb, nullptr, 256, arena+OFF_NQM, qb, xc, 256, 2, 256, nullptr, nullptr);
    else
      gemm<0,1><<<dim3(MTILES*2), dim3(256), 0, stream>>>(xm, nullptr, 256, wtn, qbt, xc, 256, 2, 256, nullptr, nullptr);
    // h = mix(relu(xc@t0^T), relu(xc@t1^T))   [fused dual-half GEMM]
    gemm<1,1><<<dim3(MTILES*2), dim3(256), 0, stream>>>(xc, nullptr, 256, arena+OFF_TCAT + l*131072, tb + l*512, hb, 256, 2, 256, mask, nullptr);
    // xw = h @ gat_W^T
    gemm<0,0><<<dim3(MTILES*2), dim3(256), 0, stream>>>(hb, nullptr, 256, arena+OFF_GAT + l*65536, nullptr, xw, 256, 2, 256, nullptr, nullptr);
    dotav<<<dim3(12500), dim3(256), 0, stream>>>(xw, gatAs + l*256, gatAd + l*256, avs, avd);
    agg  <<<dim3(12500), dim3(256), 0, stream>>>(offs, ssrc, avs, avd, xw, gatB + l*256, hgat);
    // cgn stats -> fold into ccat weights
    hipMemsetAsync(sums, 0, 2048, stream);
    colstats  <<<dim3(1024), dim3(256), 0, stream>>>(hgat, sums);
    scaleshift<<<dim3(1), dim3(256), 0, stream>>>(sums, cgnW + l*256, cgnB + l*256, cgnA + l*256, scaleC, shiftC);
    foldw     <<<dim3(512), dim3(256), 0, stream>>>(arena+OFF_CCAT + l*262144, cb + l*512, scaleC, shiftC, 512, wtc, btc);
    // xm = mix(hc@c0'^T, hc@c1'^T) + masked col stats    [fused dual-half GEMM, split A = [hgat|xc]]
    hipMemsetAsync(sums, 0, 2048, stream);
    gemm<2,0><<<dim3(MTILES*2), dim3(256), 0, stream>>>(hgat, xc, 256, wtc, btc, xm, 256, 2, 512, mask, sums);
    scaleshift<<<dim3(1), dim3(256), 0, stream>>>(sums, gnW + l*256, gnB + l*256, gnA + l*256, scaleG, shiftG);
    if (l == 0)
      foldw<<<dim3(256), dim3(256), 0, stream>>>(arena+OFF_NQM + 65536, qb + 256, scaleG, shiftG, 256, wtn, qbt);
  }

  // masked pooling of affine(xm) + final linear
  initneg<<<dim3(1), dim3(256), 0, stream>>>(pmax);
  hipMemsetAsync(psum, 0, 1024, stream);
  hipMemsetAsync(pcnt, 0, 4, stream);
  pool  <<<dim3(512), dim3(256), 0, stream>>>(xm, mask, scaleG, shiftG, psum, pmax, pcnt);
  finalk<<<dim3(1), dim3(256), 0, stream>>>(psum, pmax, pcnt, finW, finB, outp);
}